// Round 10
// baseline (9416.805 us; speedup 1.0000x reference)
//
#include <hip/hip_runtime.h>
#include <hip/hip_bf16.h>

// ---------------------------------------------------------------------------
// SA_NET: LSTM(4096 steps, H=512) + CNN branch + MLP head.
// Round 9: r7 revert (dwordx4 poll, u64 (tag|h) words, 6.43ms proven) plus
// two critical-path shaves:
//  (a) publish via raw asm global_atomic_swap_x2 with NO return operand --
//      r7's exchange+sink forced s_waitcnt vmcnt(0), stalling the writer a
//      full MALL RT before its next-step poll could start;
//  (b) gate activations computed per-lane BEFORE the gather (parallel
//      transcendentals); post-gather chain is fma+tanh+mul only.
// r8's staggered 3-slot poll regressed (flight-bound detection) - dropped.
// ---------------------------------------------------------------------------

#define HSZ   512
#define ESZ   300
#define NBLK  64      // LSTM blocks: block b owns j in [8b, 8b+8)

typedef unsigned long long u64t;
typedef float f32x4 __attribute__((ext_vector_type(4)));
typedef unsigned u32x4 __attribute__((ext_vector_type(4)));

__device__ __forceinline__ float sigf(float x) {
    return 1.f / (1.f + __expf(-x));
}
__device__ __forceinline__ float tanh_fast(float x) {
    return 1.f - 2.f / (__expf(2.f * x) + 1.f);
}

// opaque global load: compiler cannot rematerialize -> must keep in VGPRs
__device__ __forceinline__ f32x4 ldg_f4(const f32x4* p) {
    f32x4 v;
    asm volatile("global_load_dwordx4 %0, %1, off\n\ts_waitcnt vmcnt(0)"
                 : "=v"(v) : "v"(p));
    return v;
}
// coherent 16B poll load (bypasses L1/L2 caching; served at coherence point)
__device__ __forceinline__ u32x4 ld_x4_coh(const void* p) {
    u32x4 v;
    asm volatile("global_load_dwordx4 %0, %1, off sc0 sc1\n\ts_waitcnt vmcnt(0)"
                 : "=v"(v) : "v"(p) : "memory");
    return v;
}
// fire-and-forget 64-bit atomic swap: RMW executes at the device coherence
// point (keeps the line LLC-resident, r6/r7 evidence) but returns nothing,
// so the writer never stalls on vmcnt.
__device__ __forceinline__ void atomic_swap_noret(u64t* p, u64t v) {
    asm volatile("global_atomic_swap_x2 %0, %1, off"
                 :: "v"(p), "v"(v) : "memory");
}
#define AGLD64(p)   __hip_atomic_load((p), __ATOMIC_RELAXED, __HIP_MEMORY_SCOPE_AGENT)

// ---------------------------------------------------------------------------
// Persistent LSTM. 64 blocks x 256 threads. dot = tid>>3 (0..31) ->
// (jl = dot>>2, gate = dot&3); seg = tid&7 covers 64 h-elems of the dot.
// h exchange: hpack[2][512] u64 = (step<<32)|f32bits (full precision).
// Publish: no-return atomic swap. Poll: one dwordx4 coherent load covering
// the thread's two u64 words as [h0,tag0,h1,tag1]; loop until tags match.
// ---------------------------------------------------------------------------
__global__ __attribute__((amdgpu_flat_work_group_size(256, 256),
                          amdgpu_waves_per_eu(1, 1)))
void lstm_fast(
    const float* __restrict__ G, const float* __restrict__ w_hh,
    u64t* hpack /*2*512*/, float* hmean /*512*/, int T)
{
    __shared__ float hlds[2][512];
    const int tid  = threadIdx.x;
    const int lane = tid & 63;
    const int wave = tid >> 6;
    const int dot  = tid >> 3;          // 0..31
    const int seg  = tid & 7;
    const int gate = dot & 3;
    const int jl   = dot >> 2;          // 0..7
    const int j    = blockIdx.x * 8 + jl;
    const int row  = gate * HSZ + j;

    // register-resident recurrent weights, seg-rotated chunk order
    // (conflict-free LDS reads; proven r2: bank conflicts -> 0)
    f32x4 wh[16];
    {
        const f32x4* whp = (const f32x4*)(w_hh + (size_t)row * HSZ);
#pragma unroll
        for (int i = 0; i < 16; ++i)
            wh[i] = ldg_f4(whp + (seg * 16 + ((i + seg) & 15)));
    }

    float c = 0.f, hsum = 0.f;
    const int l0 = lane & 32;
    const int j2 = blockIdx.x * 8 + wave * 2 + (lane >> 5);  // writer's h idx

    for (int s = 1; s <= T; ++s) {
        const int t = s - 1, p = t & 1;

        // x-part from G (independent of h; issued before the poll)
        float acc = (seg == 0) ? G[(size_t)t * (4 * HSZ) + row] : 0.f;

        // ---- poll h_{t}: one dwordx4 = my two u64 words (slot p, tag t) ----
        {
            const u32x4* pp = (const u32x4*)(hpack + (size_t)p * HSZ) + tid;
            const unsigned tg = (unsigned)t;
            u32x4 v = ld_x4_coh(pp);
            while (v[1] != tg || v[3] != tg)
                v = ld_x4_coh(pp);
            hlds[p][2 * tid]     = __uint_as_float(v[0]);
            hlds[p][2 * tid + 1] = __uint_as_float(v[2]);
        }
        __syncthreads();   // parity double-buffer: one barrier per step

        // ---- h-matvec from LDS (rotated -> conflict-free) ----
        {
            const f32x4* hp = (const f32x4*)(&hlds[p][0]);
#pragma unroll
            for (int i = 0; i < 16; ++i) {
                f32x4 h4 = hp[seg * 16 + ((i + seg) & 15)];
                acc += wh[i][0] * h4[0] + wh[i][1] * h4[1] +
                       wh[i][2] * h4[2] + wh[i][3] * h4[3];
            }
        }
        // reduce across the 8 seg lanes
        acc += __shfl_xor(acc, 4, 64);
        acc += __shfl_xor(acc, 2, 64);
        acc += __shfl_xor(acc, 1, 64);

        // pre-activate on own lane (parallel transcendentals): gate lanes
        // l0+{0,8,16,24} hold i,f,g,o; g gets tanh, others sigmoid.
        float act = (gate == 2) ? tanh_fast(acc) : sigf(acc);

        // gather ACTIVATED gates of my half-wave's j
        float is = __shfl(act, l0 + 0,  64);
        float fs = __shfl(act, l0 + 8,  64);
        float gt = __shfl(act, l0 + 16, 64);
        float os = __shfl(act, l0 + 24, 64);

        c = fs * c + is * gt;
        float h = os * tanh_fast(c);

        if ((lane & 31) == 0) {
            union { float f; unsigned u; } hv; hv.f = h;
            u64t pk = ((u64t)(unsigned)s << 32) | (u64t)hv.u;
            // fire-and-forget RMW publish: no vmcnt stall on the writer
            atomic_swap_noret(&hpack[(size_t)(s & 1) * HSZ + j2], pk);
            hsum += h;
        }
    }

    if ((lane & 31) == 0)
        hmean[j2] = hsum * (1.f / (float)T);
}

// ---------------------------------------------------------------------------
// Fallback LSTM (no G buffer): r2-proven u64 tag scheme, 64 blocks.
// ---------------------------------------------------------------------------
__global__ __launch_bounds__(256, 1) void lstm_small(
    const float* __restrict__ inputs, const float* __restrict__ w_ih,
    const float* __restrict__ w_hh, const float* __restrict__ b_ih,
    const float* __restrict__ b_hh,
    u64t* hpack, float* hmean, int T)
{
    __shared__ float hlds[2][512];
    const int tid  = threadIdx.x;
    const int lane = tid & 63;
    const int wave = tid >> 6;
    const int dot  = tid >> 3;
    const int seg  = tid & 7;
    const int gate = dot & 3;
    const int jl   = dot >> 2;
    const int j    = blockIdx.x * 8 + jl;
    const int row  = gate * HSZ + j;

    f32x4 wh[16]; int offs[16];
    const f32x4* whp = (const f32x4*)(w_hh + (size_t)row * HSZ);
#pragma unroll
    for (int i = 0; i < 16; ++i) {
        int cc = seg * 16 + ((i + seg) & 15);
        offs[i] = cc;
        wh[i] = ldg_f4(whp + cc);
    }
    const int base = (seg == 7) ? 260 : seg * 40;
    float wx[40];
#pragma unroll
    for (int i = 0; i < 40; ++i) {
        bool valid = (seg < 7) || (i >= 20);
        wx[i] = valid ? w_ih[(size_t)row * ESZ + base + i] : 0.f;
    }
    const float bias = b_ih[row] + b_hh[row];

    float c = 0.f, hsum = 0.f;
    const int l0 = lane & 32;
    const int j2 = blockIdx.x * 8 + wave * 2 + (lane >> 5);

    for (int s = 1; s <= T; ++s) {
        const int t = s - 1, p = t & 1;
        float acc = (seg == 0) ? bias : 0.f;
        const float4* xp4 = (const float4*)(inputs + (size_t)t * ESZ + base);
#pragma unroll
        for (int i4 = 0; i4 < 10; ++i4) {
            float4 x4 = xp4[i4];
            acc += wx[i4*4+0]*x4.x + wx[i4*4+1]*x4.y +
                   wx[i4*4+2]*x4.z + wx[i4*4+3]*x4.w;
        }
        {
            u64t* w0p = hpack + (size_t)p * HSZ + tid;
            u64t* w1p = w0p + 256;
            const unsigned tg = (unsigned)t;
            u64t v0 = AGLD64(w0p), v1 = AGLD64(w1p);
            bool r0 = false, r1 = false;
            while (true) {
                r0 = r0 || ((unsigned)(v0 >> 32) == tg);
                r1 = r1 || ((unsigned)(v1 >> 32) == tg);
                if (r0 && r1) break;
                u64t n0 = AGLD64(w0p), n1 = AGLD64(w1p);
                if (!r0) v0 = n0;
                if (!r1) v1 = n1;
            }
            hlds[p][tid]       = __uint_as_float((unsigned)v0);
            hlds[p][tid + 256] = __uint_as_float((unsigned)v1);
        }
        __syncthreads();
        const f32x4* hp = (const f32x4*)(&hlds[p][0]);
#pragma unroll
        for (int i = 0; i < 16; ++i) {
            f32x4 h4 = hp[offs[i]];
            acc += wh[i][0]*h4[0] + wh[i][1]*h4[1] + wh[i][2]*h4[2] + wh[i][3]*h4[3];
        }
        acc += __shfl_xor(acc, 4, 64);
        acc += __shfl_xor(acc, 2, 64);
        acc += __shfl_xor(acc, 1, 64);
        float gi = __shfl(acc, l0 + 0,  64);
        float gf = __shfl(acc, l0 + 8,  64);
        float gg = __shfl(acc, l0 + 16, 64);
        float go = __shfl(acc, l0 + 24, 64);
        float is = sigf(gi), fs = sigf(gf), os = sigf(go);
        float gt = tanh_fast(gg);
        c = fs * c + is * gt;
        float h = os * tanh_fast(c);
        if ((lane & 31) == 0) {
            union { float f; unsigned u; } hv; hv.f = h;
            __hip_atomic_store(&hpack[(size_t)(s & 1) * HSZ + j2],
                               ((u64t)(unsigned)s << 32) | (u64t)hv.u,
                               __ATOMIC_RELAXED, __HIP_MEMORY_SCOPE_AGENT);
            hsum += h;
        }
    }
    if ((lane & 31) == 0) hmean[j2] = hsum * (1.f / (float)T);
}

// ---------------------------------------------------------------------------
// G = inputs[M,K] * w_ih[N,K]^T + (b_ih+b_hh)  — 64x64 tile, 4x4/thread
// ---------------------------------------------------------------------------
__global__ __launch_bounds__(256) void gemm_g(
    const float* __restrict__ A, const float* __restrict__ B,
    const float* __restrict__ bi, const float* __restrict__ bh,
    float* __restrict__ C, int M, int N, int K)
{
    __shared__ float As[16][65];
    __shared__ float Bs[16][65];
    const int tid = threadIdx.x;
    const int m0 = blockIdx.y * 64, n0 = blockIdx.x * 64;
    const int tm = (tid >> 4) * 4, tn = (tid & 15) * 4;
    const int lr = tid >> 2;
    const int lk = (tid & 3) * 4;
    float acc[4][4] = {};

    for (int kk = 0; kk < K; kk += 16) {
        int k0 = kk + lk;
        float4 av = {0,0,0,0}, bv = {0,0,0,0};
        if (m0 + lr < M) {
            const float* ap = A + (size_t)(m0 + lr) * K;
            if (k0 + 3 < K) av = *(const float4*)(ap + k0);
            else {
                float tmp[4];
#pragma unroll
                for (int e = 0; e < 4; ++e) tmp[e] = (k0 + e < K) ? ap[k0 + e] : 0.f;
                av.x = tmp[0]; av.y = tmp[1]; av.z = tmp[2]; av.w = tmp[3];
            }
        }
        {
            const float* bp = B + (size_t)(n0 + lr) * K;
            if (k0 + 3 < K) bv = *(const float4*)(bp + k0);
            else {
                float tmp[4];
#pragma unroll
                for (int e = 0; e < 4; ++e) tmp[e] = (k0 + e < K) ? bp[k0 + e] : 0.f;
                bv.x = tmp[0]; bv.y = tmp[1]; bv.z = tmp[2]; bv.w = tmp[3];
            }
        }
        As[lk+0][lr] = av.x; As[lk+1][lr] = av.y;
        As[lk+2][lr] = av.z; As[lk+3][lr] = av.w;
        Bs[lk+0][lr] = bv.x; Bs[lk+1][lr] = bv.y;
        Bs[lk+2][lr] = bv.z; Bs[lk+3][lr] = bv.w;
        __syncthreads();
#pragma unroll
        for (int k2 = 0; k2 < 16; ++k2) {
            float a0 = As[k2][tm], a1 = As[k2][tm+1], a2 = As[k2][tm+2], a3 = As[k2][tm+3];
            float b0 = Bs[k2][tn], b1 = Bs[k2][tn+1], b2 = Bs[k2][tn+2], b3 = Bs[k2][tn+3];
            acc[0][0]+=a0*b0; acc[0][1]+=a0*b1; acc[0][2]+=a0*b2; acc[0][3]+=a0*b3;
            acc[1][0]+=a1*b0; acc[1][1]+=a1*b1; acc[1][2]+=a1*b2; acc[1][3]+=a1*b3;
            acc[2][0]+=a2*b0; acc[2][1]+=a2*b1; acc[2][2]+=a2*b2; acc[2][3]+=a2*b3;
            acc[3][0]+=a3*b0; acc[3][1]+=a3*b1; acc[3][2]+=a3*b2; acc[3][3]+=a3*b3;
        }
        __syncthreads();
    }
#pragma unroll
    for (int i = 0; i < 4; ++i) {
        int m = m0 + tm + i;
        if (m >= M) break;
#pragma unroll
        for (int jj = 0; jj < 4; ++jj) {
            int n = n0 + tn + jj;
            C[(size_t)m * N + n] = acc[i][jj] + bi[n] + bh[n];
        }
    }
}

// ---------------------------------------------------------------------------
// Generic tiled fp32 GEMM for CNN: C[M,N] = A[M,K]*B[N,K]^T + bias[n]
// ---------------------------------------------------------------------------
__global__ __launch_bounds__(256) void gemm32(
    const float* __restrict__ A, const float* __restrict__ B,
    const float* __restrict__ bias, float* __restrict__ C,
    int M, int N, int K)
{
    __shared__ float As[32][33];
    __shared__ float Bs[32][33];
    const int tid = threadIdx.x;
    const int m0 = blockIdx.y * 32, n0 = blockIdx.x * 32;
    const int tn = (tid & 15) * 2, tm = (tid >> 4) * 2;
    float a00 = 0, a01 = 0, a10 = 0, a11 = 0;

    for (int kk = 0; kk < K; kk += 32) {
        const int k = tid & 31, r = tid >> 5;
#pragma unroll
        for (int jj = 0; jj < 4; ++jj) {
            int m = r + jj * 8;
            As[k][m] = (kk + k < K && m0 + m < M) ? A[(size_t)(m0+m)*K + kk+k] : 0.f;
            Bs[k][m] = (kk + k < K && n0 + m < N) ? B[(size_t)(n0+m)*K + kk+k] : 0.f;
        }
        __syncthreads();
#pragma unroll
        for (int k2 = 0; k2 < 32; ++k2) {
            float x0 = As[k2][tm], x1 = As[k2][tm+1];
            float y0 = Bs[k2][tn], y1 = Bs[k2][tn+1];
            a00 += x0*y0; a01 += x0*y1; a10 += x1*y0; a11 += x1*y1;
        }
        __syncthreads();
    }
    const int m = m0 + tm, n = n0 + tn;
    if (m < M) {
        if (n     < N) C[(size_t)m*N + n]     = a00 + bias[n];
        if (n + 1 < N) C[(size_t)m*N + n + 1] = a01 + bias[n+1];
    }
    if (m + 1 < M) {
        if (n     < N) C[(size_t)(m+1)*N + n]     = a10 + bias[n];
        if (n + 1 < N) C[(size_t)(m+1)*N + n + 1] = a11 + bias[n+1];
    }
}

__global__ void im2col1(const float* __restrict__ in, float* __restrict__ X)
{
    int idx = blockIdx.x * 256 + threadIdx.x;
    if (idx >= 512 * 2100) return;
    int t = idx / 2100, k = idx - t * 2100;
    int dt = k / 300, e = k - dt * 300;
    int tt = t + dt - 3;
    X[idx] = (tt >= 0 && tt < 512) ? in[tt * 300 + e] : 0.f;
}

__global__ void im2colN(const float* __restrict__ S, float* __restrict__ X,
                        int L, int Cin, int KW, int pad, int total)
{
    int idx = blockIdx.x * 256 + threadIdx.x;
    if (idx >= total) return;
    int KC = Cin * KW;
    int t = idx / KC, r = idx - t * KC;
    int c = r / KW, dk = r - c * KW;
    int tt = t + dk - pad;
    X[idx] = (tt >= 0 && tt < L) ? S[c * L + tt] : 0.f;
}

__global__ void transpose4(const float* __restrict__ S, float* __restrict__ X)
{
    int idx = blockIdx.x * 256 + threadIdx.x;
    if (idx >= 64 * 256) return;
    int t = idx >> 8, c = idx & 255;
    X[idx] = S[c * 64 + t];
}

__global__ void poolsig(const float* __restrict__ Cin_, float* __restrict__ S,
                        int Cch, int LP)
{
    int idx = blockIdx.x * 256 + threadIdx.x;
    if (idx >= Cch * LP) return;
    int c = idx / LP, tp = idx - c * LP;
    float a = Cin_[(2 * tp) * Cch + c];
    float b = Cin_[(2 * tp + 1) * Cch + c];
    S[idx] = sigf(fmaxf(a, b));
}

__global__ void sigy(const float* __restrict__ C4, float* __restrict__ y)
{
    int idx = blockIdx.x * 256 + threadIdx.x;
    if (idx >= 1024) return;
    int o = idx >> 6, t = idx & 63;
    y[idx] = sigf(C4[t * 16 + o]);
}

__global__ void fc1_kernel(const float* __restrict__ hmean,
                           const float* __restrict__ y,
                           const float* __restrict__ w,
                           const float* __restrict__ b,
                           float* __restrict__ out)
{
    int k = blockIdx.x, lane = threadIdx.x;
    float a = 0.f;
    for (int i = lane; i < 1536; i += 64) {
        float xv = (i < 512) ? hmean[i] : y[i - 512];
        a += xv * w[k * 1536 + i];
    }
#pragma unroll
    for (int off = 32; off; off >>= 1) a += __shfl_xor(a, off, 64);
    if (lane == 0) out[k] = sigf(a + b[k]);
}

__global__ void head_kernel(const float* __restrict__ x2,
                            const float* __restrict__ w2, const float* __restrict__ b2,
                            const float* __restrict__ w3, const float* __restrict__ b3,
                            float* __restrict__ out)
{
    __shared__ float x3[32];
    int lane = threadIdx.x;
    if (lane < 32) {
        float a = 0.f;
        for (int i = 0; i < 128; ++i) a += x2[i] * w2[lane * 128 + i];
        x3[lane] = sigf(a + b2[lane]);
    }
    __syncthreads();
    if (lane == 0) {
        float a = 0.f;
        for (int i = 0; i < 32; ++i) a += x3[i] * w3[i];
        out[0] = sigf(a + b3[0]);
    }
}

extern "C" void kernel_launch(void* const* d_in, const int* in_sizes, int n_in,
                              void* d_out, int out_size, void* d_ws, size_t ws_size,
                              hipStream_t stream)
{
    const float* inputs = (const float*)d_in[0];
    const float* w_ih   = (const float*)d_in[1];
    const float* w_hh   = (const float*)d_in[2];
    const float* b_ih   = (const float*)d_in[3];
    const float* b_hh   = (const float*)d_in[4];
    const float* c1w    = (const float*)d_in[5];
    const float* c1b    = (const float*)d_in[6];
    const float* c2w    = (const float*)d_in[7];
    const float* c2b    = (const float*)d_in[8];
    const float* c3w    = (const float*)d_in[9];
    const float* c3b    = (const float*)d_in[10];
    const float* c4w    = (const float*)d_in[11];
    const float* c4b    = (const float*)d_in[12];
    const float* fc1w   = (const float*)d_in[13];
    const float* fc1b   = (const float*)d_in[14];
    const float* fc2w   = (const float*)d_in[15];
    const float* fc2b   = (const float*)d_in[16];
    const float* fc3w   = (const float*)d_in[17];
    const float* fc3b   = (const float*)d_in[18];
    float* out = (float*)d_out;
    const int T = in_sizes[0] / ESZ;   // 4096

    // ---- workspace layout (floats) ----
    // [0,2048): hpack (2*512 u64 = 8KB)
    // 2048: hmean(512)   2560: CNN buffers   then G.
    float*    p     = (float*)d_ws;
    u64t*     hpack = (u64t*)d_ws;              // 2*512 u64
    float* hmean = p + 2048;                    // 512
    float* X1 = p + 2560;                       // 512*2100 = 1075200
    float* C1 = X1 + 1075200;                   // 512*256
    float* s1 = C1 + 131072;                    // 256*256
    float* X2 = s1 + 65536;                     // 256*1280
    float* C2 = X2 + 327680;                    // 256*64
    float* s2 = C2 + 16384;                     // 64*128
    float* X3 = s2 + 8192;                      // 128*192
    float* C3 = X3 + 24576;                     // 128*256
    float* s3 = C3 + 32768;                     // 256*64
    float* X4 = s3 + 16384;                     // 64*256
    float* C4 = X4 + 16384;                     // 64*16
    float* yb = C4 + 1024;                      // 1024
    float* x2 = yb + 1024;                      // 128
    float* G  = x2 + 128;                       // T*2048 floats (32MB @ T=4096)
    const size_t need_bytes = ((size_t)(x2 + 128 - p) + (size_t)T * 2048) * 4;
    const bool use_g = ws_size >= need_bytes;

    // zero h state (h_0 = 0 with tag 0) — replay-safe
    hipMemsetAsync(d_ws, 0, 8192, stream);

    if (use_g) {
        gemm_g<<<dim3(2048 / 64, (T + 63) / 64), 256, 0, stream>>>(
            inputs, w_ih, b_ih, b_hh, G, T, 2048, ESZ);
        lstm_fast<<<NBLK, 256, 0, stream>>>(G, w_hh, hpack, hmean, T);
    } else {
        lstm_small<<<NBLK, 256, 0, stream>>>(
            inputs, w_ih, w_hh, b_ih, b_hh, hpack, hmean, T);
    }

    // ---- CNN branch ----
    im2col1<<<4200, 256, 0, stream>>>(inputs, X1);
    gemm32<<<dim3(8, 16), 256, 0, stream>>>(X1, c1w, c1b, C1, 512, 256, 2100);
    poolsig<<<256, 256, 0, stream>>>(C1, s1, 256, 256);

    im2colN<<<1280, 256, 0, stream>>>(s1, X2, 256, 256, 5, 2, 256 * 1280);
    gemm32<<<dim3(2, 8), 256, 0, stream>>>(X2, c2w, c2b, C2, 256, 64, 1280);
    poolsig<<<32, 256, 0, stream>>>(C2, s2, 64, 128);

    im2colN<<<96, 256, 0, stream>>>(s2, X3, 128, 64, 3, 1, 128 * 192);
    gemm32<<<dim3(8, 4), 256, 0, stream>>>(X3, c3w, c3b, C3, 128, 256, 192);
    poolsig<<<64, 256, 0, stream>>>(C3, s3, 256, 64);

    transpose4<<<64, 256, 0, stream>>>(s3, X4);
    gemm32<<<dim3(1, 2), 256, 0, stream>>>(X4, c4w, c4b, C4, 64, 16, 256);
    sigy<<<4, 256, 0, stream>>>(C4, yb);

    // ---- MLP head ----
    fc1_kernel<<<128, 64, 0, stream>>>(hmean, yb, fc1w, fc1b, x2);
    head_kernel<<<1, 64, 0, stream>>>(x2, fc2w, fc2b, fc3w, fc3b, out);
}

// Round 11
// 6942.723 us; speedup vs baseline: 1.3564x; 1.3564x over previous
//
#include <hip/hip_runtime.h>
#include <hip/hip_bf16.h>

// ---------------------------------------------------------------------------
// SA_NET: LSTM(4096 steps, H=512) + CNN branch + MLP head.
// Round 10: EXACT revert to round 7 (best proven: 6.43ms LSTM, 7.12ms total).
// Sync scheme: writers publish h via u64 atomic EXCHANGE WITH RETURN (the
// returned RMW is what keeps the line at the device coherence point --
// r6/r7/r9 triangulation), readers poll via plain coherent dwordx4 loads
// (no serialization; tag-checked). r8 (staggered polls) and r9 (no-return
// swap + pre-gather activations) both regressed and are dropped.
// ---------------------------------------------------------------------------

#define HSZ   512
#define ESZ   300
#define NBLK  64      // LSTM blocks: block b owns j in [8b, 8b+8)

typedef unsigned long long u64t;
typedef float f32x4 __attribute__((ext_vector_type(4)));
typedef unsigned u32x4 __attribute__((ext_vector_type(4)));

__device__ __forceinline__ float sigf(float x) {
    return 1.f / (1.f + __expf(-x));
}
__device__ __forceinline__ float tanh_fast(float x) {
    return 1.f - 2.f / (__expf(2.f * x) + 1.f);
}

// opaque global load: compiler cannot rematerialize -> must keep in VGPRs
__device__ __forceinline__ f32x4 ldg_f4(const f32x4* p) {
    f32x4 v;
    asm volatile("global_load_dwordx4 %0, %1, off\n\ts_waitcnt vmcnt(0)"
                 : "=v"(v) : "v"(p));
    return v;
}
// coherent 16B poll load (bypasses L1/L2 caching; served at coherence point)
__device__ __forceinline__ u32x4 ld_x4_coh(const void* p) {
    u32x4 v;
    asm volatile("global_load_dwordx4 %0, %1, off sc0 sc1\n\ts_waitcnt vmcnt(0)"
                 : "=v"(v) : "v"(p) : "memory");
    return v;
}
#define AGLD64(p)   __hip_atomic_load((p), __ATOMIC_RELAXED, __HIP_MEMORY_SCOPE_AGENT)

// ---------------------------------------------------------------------------
// Persistent LSTM. 64 blocks x 256 threads. dot = tid>>3 (0..31) ->
// (jl = dot>>2, gate = dot&3); seg = tid&7 covers 64 h-elems of the dot.
// h exchange: hpack[2][512] u64 = (step<<32)|f32bits.
// Publish: atomic exchange with returned value (line installed + kept at
// the coherence point). Poll: one dwordx4 plain coherent load per thread =
// words {2tid, 2tid+1} as [h0,tag0,h1,tag1]; loop until both tags match.
// ---------------------------------------------------------------------------
__global__ __attribute__((amdgpu_flat_work_group_size(256, 256),
                          amdgpu_waves_per_eu(1, 1)))
void lstm_fast(
    const float* __restrict__ G, const float* __restrict__ w_hh,
    u64t* hpack /*2*512*/, float* hmean /*512*/, int T)
{
    __shared__ float hlds[2][512];
    const int tid  = threadIdx.x;
    const int lane = tid & 63;
    const int wave = tid >> 6;
    const int dot  = tid >> 3;          // 0..31
    const int seg  = tid & 7;
    const int gate = dot & 3;
    const int jl   = dot >> 2;          // 0..7
    const int j    = blockIdx.x * 8 + jl;
    const int row  = gate * HSZ + j;

    // register-resident recurrent weights, seg-rotated chunk order
    // (conflict-free LDS reads; proven r2: bank conflicts -> 0)
    f32x4 wh[16];
    {
        const f32x4* whp = (const f32x4*)(w_hh + (size_t)row * HSZ);
#pragma unroll
        for (int i = 0; i < 16; ++i)
            wh[i] = ldg_f4(whp + (seg * 16 + ((i + seg) & 15)));
    }

    float c = 0.f, hsum = 0.f;
    const int l0 = lane & 32;
    const int j2 = blockIdx.x * 8 + wave * 2 + (lane >> 5);  // writer's h idx

    for (int s = 1; s <= T; ++s) {
        const int t = s - 1, p = t & 1;

        // x-part from G (independent of h; issued before the poll)
        float acc = (seg == 0) ? G[(size_t)t * (4 * HSZ) + row] : 0.f;

        // ---- poll h_{t}: one dwordx4 = my two u64 words (slot p, tag t) ----
        {
            const u32x4* pp = (const u32x4*)(hpack + (size_t)p * HSZ) + tid;
            const unsigned tg = (unsigned)t;
            u32x4 v = ld_x4_coh(pp);
            while (v[1] != tg || v[3] != tg)
                v = ld_x4_coh(pp);
            hlds[p][2 * tid]     = __uint_as_float(v[0]);
            hlds[p][2 * tid + 1] = __uint_as_float(v[2]);
        }
        __syncthreads();   // parity double-buffer: one barrier per step

        // ---- h-matvec from LDS (rotated -> conflict-free) ----
        {
            const f32x4* hp = (const f32x4*)(&hlds[p][0]);
#pragma unroll
            for (int i = 0; i < 16; ++i) {
                f32x4 h4 = hp[seg * 16 + ((i + seg) & 15)];
                acc += wh[i][0] * h4[0] + wh[i][1] * h4[1] +
                       wh[i][2] * h4[2] + wh[i][3] * h4[3];
            }
        }
        // reduce across the 8 seg lanes
        acc += __shfl_xor(acc, 4, 64);
        acc += __shfl_xor(acc, 2, 64);
        acc += __shfl_xor(acc, 1, 64);
        // gather the 4 gates of my half-wave's j
        float gi = __shfl(acc, l0 + 0,  64);
        float gf = __shfl(acc, l0 + 8,  64);
        float gg = __shfl(acc, l0 + 16, 64);
        float go = __shfl(acc, l0 + 24, 64);

        float is = sigf(gi), fs = sigf(gf), os = sigf(go);
        float gt = tanh_fast(gg);
        c = fs * c + is * gt;
        float h = os * tanh_fast(c);

        if ((lane & 31) == 0) {
            hsum += h;
            union { float f; unsigned u; } hv; hv.f = h;
            u64t pk = ((u64t)(unsigned)s << 32) | (u64t)hv.u;
            // publish via RMW: installs the line at the coherence point so
            // the readers' loads hit LLC instead of HBM (r6 evidence)
            u64t old = __hip_atomic_exchange(
                &hpack[(size_t)(s & 1) * HSZ + j2], pk,
                __ATOMIC_RELAXED, __HIP_MEMORY_SCOPE_AGENT);
            asm volatile("" :: "v"(old));   // keep the RMW (no store demotion)
        }
    }

    if ((lane & 31) == 0)
        hmean[j2] = hsum * (1.f / (float)T);
}

// ---------------------------------------------------------------------------
// Fallback LSTM (no G buffer): r2-proven u64 tag scheme, 64 blocks.
// ---------------------------------------------------------------------------
__global__ __launch_bounds__(256, 1) void lstm_small(
    const float* __restrict__ inputs, const float* __restrict__ w_ih,
    const float* __restrict__ w_hh, const float* __restrict__ b_ih,
    const float* __restrict__ b_hh,
    u64t* hpack, float* hmean, int T)
{
    __shared__ float hlds[2][512];
    const int tid  = threadIdx.x;
    const int lane = tid & 63;
    const int wave = tid >> 6;
    const int dot  = tid >> 3;
    const int seg  = tid & 7;
    const int gate = dot & 3;
    const int jl   = dot >> 2;
    const int j    = blockIdx.x * 8 + jl;
    const int row  = gate * HSZ + j;

    f32x4 wh[16]; int offs[16];
    const f32x4* whp = (const f32x4*)(w_hh + (size_t)row * HSZ);
#pragma unroll
    for (int i = 0; i < 16; ++i) {
        int cc = seg * 16 + ((i + seg) & 15);
        offs[i] = cc;
        wh[i] = ldg_f4(whp + cc);
    }
    const int base = (seg == 7) ? 260 : seg * 40;
    float wx[40];
#pragma unroll
    for (int i = 0; i < 40; ++i) {
        bool valid = (seg < 7) || (i >= 20);
        wx[i] = valid ? w_ih[(size_t)row * ESZ + base + i] : 0.f;
    }
    const float bias = b_ih[row] + b_hh[row];

    float c = 0.f, hsum = 0.f;
    const int l0 = lane & 32;
    const int j2 = blockIdx.x * 8 + wave * 2 + (lane >> 5);

    for (int s = 1; s <= T; ++s) {
        const int t = s - 1, p = t & 1;
        float acc = (seg == 0) ? bias : 0.f;
        const float4* xp4 = (const float4*)(inputs + (size_t)t * ESZ + base);
#pragma unroll
        for (int i4 = 0; i4 < 10; ++i4) {
            float4 x4 = xp4[i4];
            acc += wx[i4*4+0]*x4.x + wx[i4*4+1]*x4.y +
                   wx[i4*4+2]*x4.z + wx[i4*4+3]*x4.w;
        }
        {
            u64t* w0p = hpack + (size_t)p * HSZ + tid;
            u64t* w1p = w0p + 256;
            const unsigned tg = (unsigned)t;
            u64t v0 = AGLD64(w0p), v1 = AGLD64(w1p);
            bool r0 = false, r1 = false;
            while (true) {
                r0 = r0 || ((unsigned)(v0 >> 32) == tg);
                r1 = r1 || ((unsigned)(v1 >> 32) == tg);
                if (r0 && r1) break;
                u64t n0 = AGLD64(w0p), n1 = AGLD64(w1p);
                if (!r0) v0 = n0;
                if (!r1) v1 = n1;
            }
            hlds[p][tid]       = __uint_as_float((unsigned)v0);
            hlds[p][tid + 256] = __uint_as_float((unsigned)v1);
        }
        __syncthreads();
        const f32x4* hp = (const f32x4*)(&hlds[p][0]);
#pragma unroll
        for (int i = 0; i < 16; ++i) {
            f32x4 h4 = hp[offs[i]];
            acc += wh[i][0]*h4[0] + wh[i][1]*h4[1] + wh[i][2]*h4[2] + wh[i][3]*h4[3];
        }
        acc += __shfl_xor(acc, 4, 64);
        acc += __shfl_xor(acc, 2, 64);
        acc += __shfl_xor(acc, 1, 64);
        float gi = __shfl(acc, l0 + 0,  64);
        float gf = __shfl(acc, l0 + 8,  64);
        float gg = __shfl(acc, l0 + 16, 64);
        float go = __shfl(acc, l0 + 24, 64);
        float is = sigf(gi), fs = sigf(gf), os = sigf(go);
        float gt = tanh_fast(gg);
        c = fs * c + is * gt;
        float h = os * tanh_fast(c);
        if ((lane & 31) == 0) {
            union { float f; unsigned u; } hv; hv.f = h;
            __hip_atomic_store(&hpack[(size_t)(s & 1) * HSZ + j2],
                               ((u64t)(unsigned)s << 32) | (u64t)hv.u,
                               __ATOMIC_RELAXED, __HIP_MEMORY_SCOPE_AGENT);
            hsum += h;
        }
    }
    if ((lane & 31) == 0) hmean[j2] = hsum * (1.f / (float)T);
}

// ---------------------------------------------------------------------------
// G = inputs[M,K] * w_ih[N,K]^T + (b_ih+b_hh)  — 64x64 tile, 4x4/thread
// ---------------------------------------------------------------------------
__global__ __launch_bounds__(256) void gemm_g(
    const float* __restrict__ A, const float* __restrict__ B,
    const float* __restrict__ bi, const float* __restrict__ bh,
    float* __restrict__ C, int M, int N, int K)
{
    __shared__ float As[16][65];
    __shared__ float Bs[16][65];
    const int tid = threadIdx.x;
    const int m0 = blockIdx.y * 64, n0 = blockIdx.x * 64;
    const int tm = (tid >> 4) * 4, tn = (tid & 15) * 4;
    const int lr = tid >> 2;
    const int lk = (tid & 3) * 4;
    float acc[4][4] = {};

    for (int kk = 0; kk < K; kk += 16) {
        int k0 = kk + lk;
        float4 av = {0,0,0,0}, bv = {0,0,0,0};
        if (m0 + lr < M) {
            const float* ap = A + (size_t)(m0 + lr) * K;
            if (k0 + 3 < K) av = *(const float4*)(ap + k0);
            else {
                float tmp[4];
#pragma unroll
                for (int e = 0; e < 4; ++e) tmp[e] = (k0 + e < K) ? ap[k0 + e] : 0.f;
                av.x = tmp[0]; av.y = tmp[1]; av.z = tmp[2]; av.w = tmp[3];
            }
        }
        {
            const float* bp = B + (size_t)(n0 + lr) * K;
            if (k0 + 3 < K) bv = *(const float4*)(bp + k0);
            else {
                float tmp[4];
#pragma unroll
                for (int e = 0; e < 4; ++e) tmp[e] = (k0 + e < K) ? bp[k0 + e] : 0.f;
                bv.x = tmp[0]; bv.y = tmp[1]; bv.z = tmp[2]; bv.w = tmp[3];
            }
        }
        As[lk+0][lr] = av.x; As[lk+1][lr] = av.y;
        As[lk+2][lr] = av.z; As[lk+3][lr] = av.w;
        Bs[lk+0][lr] = bv.x; Bs[lk+1][lr] = bv.y;
        Bs[lk+2][lr] = bv.z; Bs[lk+3][lr] = bv.w;
        __syncthreads();
#pragma unroll
        for (int k2 = 0; k2 < 16; ++k2) {
            float a0 = As[k2][tm], a1 = As[k2][tm+1], a2 = As[k2][tm+2], a3 = As[k2][tm+3];
            float b0 = Bs[k2][tn], b1 = Bs[k2][tn+1], b2 = Bs[k2][tn+2], b3 = Bs[k2][tn+3];
            acc[0][0]+=a0*b0; acc[0][1]+=a0*b1; acc[0][2]+=a0*b2; acc[0][3]+=a0*b3;
            acc[1][0]+=a1*b0; acc[1][1]+=a1*b1; acc[1][2]+=a1*b2; acc[1][3]+=a1*b3;
            acc[2][0]+=a2*b0; acc[2][1]+=a2*b1; acc[2][2]+=a2*b2; acc[2][3]+=a2*b3;
            acc[3][0]+=a3*b0; acc[3][1]+=a3*b1; acc[3][2]+=a3*b2; acc[3][3]+=a3*b3;
        }
        __syncthreads();
    }
#pragma unroll
    for (int i = 0; i < 4; ++i) {
        int m = m0 + tm + i;
        if (m >= M) break;
#pragma unroll
        for (int jj = 0; jj < 4; ++jj) {
            int n = n0 + tn + jj;
            C[(size_t)m * N + n] = acc[i][jj] + bi[n] + bh[n];
        }
    }
}

// ---------------------------------------------------------------------------
// Generic tiled fp32 GEMM for CNN: C[M,N] = A[M,K]*B[N,K]^T + bias[n]
// ---------------------------------------------------------------------------
__global__ __launch_bounds__(256) void gemm32(
    const float* __restrict__ A, const float* __restrict__ B,
    const float* __restrict__ bias, float* __restrict__ C,
    int M, int N, int K)
{
    __shared__ float As[32][33];
    __shared__ float Bs[32][33];
    const int tid = threadIdx.x;
    const int m0 = blockIdx.y * 32, n0 = blockIdx.x * 32;
    const int tn = (tid & 15) * 2, tm = (tid >> 4) * 2;
    float a00 = 0, a01 = 0, a10 = 0, a11 = 0;

    for (int kk = 0; kk < K; kk += 32) {
        const int k = tid & 31, r = tid >> 5;
#pragma unroll
        for (int jj = 0; jj < 4; ++jj) {
            int m = r + jj * 8;
            As[k][m] = (kk + k < K && m0 + m < M) ? A[(size_t)(m0+m)*K + kk+k] : 0.f;
            Bs[k][m] = (kk + k < K && n0 + m < N) ? B[(size_t)(n0+m)*K + kk+k] : 0.f;
        }
        __syncthreads();
#pragma unroll
        for (int k2 = 0; k2 < 32; ++k2) {
            float x0 = As[k2][tm], x1 = As[k2][tm+1];
            float y0 = Bs[k2][tn], y1 = Bs[k2][tn+1];
            a00 += x0*y0; a01 += x0*y1; a10 += x1*y0; a11 += x1*y1;
        }
        __syncthreads();
    }
    const int m = m0 + tm, n = n0 + tn;
    if (m < M) {
        if (n     < N) C[(size_t)m*N + n]     = a00 + bias[n];
        if (n + 1 < N) C[(size_t)m*N + n + 1] = a01 + bias[n+1];
    }
    if (m + 1 < M) {
        if (n     < N) C[(size_t)(m+1)*N + n]     = a10 + bias[n];
        if (n + 1 < N) C[(size_t)(m+1)*N + n + 1] = a11 + bias[n+1];
    }
}

__global__ void im2col1(const float* __restrict__ in, float* __restrict__ X)
{
    int idx = blockIdx.x * 256 + threadIdx.x;
    if (idx >= 512 * 2100) return;
    int t = idx / 2100, k = idx - t * 2100;
    int dt = k / 300, e = k - dt * 300;
    int tt = t + dt - 3;
    X[idx] = (tt >= 0 && tt < 512) ? in[tt * 300 + e] : 0.f;
}

__global__ void im2colN(const float* __restrict__ S, float* __restrict__ X,
                        int L, int Cin, int KW, int pad, int total)
{
    int idx = blockIdx.x * 256 + threadIdx.x;
    if (idx >= total) return;
    int KC = Cin * KW;
    int t = idx / KC, r = idx - t * KC;
    int c = r / KW, dk = r - c * KW;
    int tt = t + dk - pad;
    X[idx] = (tt >= 0 && tt < L) ? S[c * L + tt] : 0.f;
}

__global__ void transpose4(const float* __restrict__ S, float* __restrict__ X)
{
    int idx = blockIdx.x * 256 + threadIdx.x;
    if (idx >= 64 * 256) return;
    int t = idx >> 8, c = idx & 255;
    X[idx] = S[c * 64 + t];
}

__global__ void poolsig(const float* __restrict__ Cin_, float* __restrict__ S,
                        int Cch, int LP)
{
    int idx = blockIdx.x * 256 + threadIdx.x;
    if (idx >= Cch * LP) return;
    int c = idx / LP, tp = idx - c * LP;
    float a = Cin_[(2 * tp) * Cch + c];
    float b = Cin_[(2 * tp + 1) * Cch + c];
    S[idx] = sigf(fmaxf(a, b));
}

__global__ void sigy(const float* __restrict__ C4, float* __restrict__ y)
{
    int idx = blockIdx.x * 256 + threadIdx.x;
    if (idx >= 1024) return;
    int o = idx >> 6, t = idx & 63;
    y[idx] = sigf(C4[t * 16 + o]);
}

__global__ void fc1_kernel(const float* __restrict__ hmean,
                           const float* __restrict__ y,
                           const float* __restrict__ w,
                           const float* __restrict__ b,
                           float* __restrict__ out)
{
    int k = blockIdx.x, lane = threadIdx.x;
    float a = 0.f;
    for (int i = lane; i < 1536; i += 64) {
        float xv = (i < 512) ? hmean[i] : y[i - 512];
        a += xv * w[k * 1536 + i];
    }
#pragma unroll
    for (int off = 32; off; off >>= 1) a += __shfl_xor(a, off, 64);
    if (lane == 0) out[k] = sigf(a + b[k]);
}

__global__ void head_kernel(const float* __restrict__ x2,
                            const float* __restrict__ w2, const float* __restrict__ b2,
                            const float* __restrict__ w3, const float* __restrict__ b3,
                            float* __restrict__ out)
{
    __shared__ float x3[32];
    int lane = threadIdx.x;
    if (lane < 32) {
        float a = 0.f;
        for (int i = 0; i < 128; ++i) a += x2[i] * w2[lane * 128 + i];
        x3[lane] = sigf(a + b2[lane]);
    }
    __syncthreads();
    if (lane == 0) {
        float a = 0.f;
        for (int i = 0; i < 32; ++i) a += x3[i] * w3[i];
        out[0] = sigf(a + b3[0]);
    }
}

extern "C" void kernel_launch(void* const* d_in, const int* in_sizes, int n_in,
                              void* d_out, int out_size, void* d_ws, size_t ws_size,
                              hipStream_t stream)
{
    const float* inputs = (const float*)d_in[0];
    const float* w_ih   = (const float*)d_in[1];
    const float* w_hh   = (const float*)d_in[2];
    const float* b_ih   = (const float*)d_in[3];
    const float* b_hh   = (const float*)d_in[4];
    const float* c1w    = (const float*)d_in[5];
    const float* c1b    = (const float*)d_in[6];
    const float* c2w    = (const float*)d_in[7];
    const float* c2b    = (const float*)d_in[8];
    const float* c3w    = (const float*)d_in[9];
    const float* c3b    = (const float*)d_in[10];
    const float* c4w    = (const float*)d_in[11];
    const float* c4b    = (const float*)d_in[12];
    const float* fc1w   = (const float*)d_in[13];
    const float* fc1b   = (const float*)d_in[14];
    const float* fc2w   = (const float*)d_in[15];
    const float* fc2b   = (const float*)d_in[16];
    const float* fc3w   = (const float*)d_in[17];
    const float* fc3b   = (const float*)d_in[18];
    float* out = (float*)d_out;
    const int T = in_sizes[0] / ESZ;   // 4096

    // ---- workspace layout (floats) ----
    // [0,2048): hpack (2*512 u64 = 8KB)
    // 2048: hmean(512)   2560: CNN buffers   then G.
    float*    p     = (float*)d_ws;
    u64t*     hpack = (u64t*)d_ws;              // 2*512 u64
    float* hmean = p + 2048;                    // 512
    float* X1 = p + 2560;                       // 512*2100 = 1075200
    float* C1 = X1 + 1075200;                   // 512*256
    float* s1 = C1 + 131072;                    // 256*256
    float* X2 = s1 + 65536;                     // 256*1280
    float* C2 = X2 + 327680;                    // 256*64
    float* s2 = C2 + 16384;                     // 64*128
    float* X3 = s2 + 8192;                      // 128*192
    float* C3 = X3 + 24576;                     // 128*256
    float* s3 = C3 + 32768;                     // 256*64
    float* X4 = s3 + 16384;                     // 64*256
    float* C4 = X4 + 16384;                     // 64*16
    float* yb = C4 + 1024;                      // 1024
    float* x2 = yb + 1024;                      // 128
    float* G  = x2 + 128;                       // T*2048 floats (32MB @ T=4096)
    const size_t need_bytes = ((size_t)(x2 + 128 - p) + (size_t)T * 2048) * 4;
    const bool use_g = ws_size >= need_bytes;

    // zero h state (h_0 = 0 with tag 0) — replay-safe
    hipMemsetAsync(d_ws, 0, 8192, stream);

    if (use_g) {
        gemm_g<<<dim3(2048 / 64, (T + 63) / 64), 256, 0, stream>>>(
            inputs, w_ih, b_ih, b_hh, G, T, 2048, ESZ);
        lstm_fast<<<NBLK, 256, 0, stream>>>(G, w_hh, hpack, hmean, T);
    } else {
        lstm_small<<<NBLK, 256, 0, stream>>>(
            inputs, w_ih, w_hh, b_ih, b_hh, hpack, hmean, T);
    }

    // ---- CNN branch ----
    im2col1<<<4200, 256, 0, stream>>>(inputs, X1);
    gemm32<<<dim3(8, 16), 256, 0, stream>>>(X1, c1w, c1b, C1, 512, 256, 2100);
    poolsig<<<256, 256, 0, stream>>>(C1, s1, 256, 256);

    im2colN<<<1280, 256, 0, stream>>>(s1, X2, 256, 256, 5, 2, 256 * 1280);
    gemm32<<<dim3(2, 8), 256, 0, stream>>>(X2, c2w, c2b, C2, 256, 64, 1280);
    poolsig<<<32, 256, 0, stream>>>(C2, s2, 64, 128);

    im2colN<<<96, 256, 0, stream>>>(s2, X3, 128, 64, 3, 1, 128 * 192);
    gemm32<<<dim3(8, 4), 256, 0, stream>>>(X3, c3w, c3b, C3, 128, 256, 192);
    poolsig<<<64, 256, 0, stream>>>(C3, s3, 256, 64);

    transpose4<<<64, 256, 0, stream>>>(s3, X4);
    gemm32<<<dim3(1, 2), 256, 0, stream>>>(X4, c4w, c4b, C4, 64, 16, 256);
    sigy<<<4, 256, 0, stream>>>(C4, yb);

    // ---- MLP head ----
    fc1_kernel<<<128, 64, 0, stream>>>(hmean, yb, fc1w, fc1b, x2);
    head_kernel<<<1, 64, 0, stream>>>(x2, fc2w, fc2b, fc3w, fc3b, out);
}

// Round 12
// 6706.694 us; speedup vs baseline: 1.4041x; 1.0352x over previous
//
#include <hip/hip_runtime.h>
#include <hip/hip_bf16.h>

// ---------------------------------------------------------------------------
// SA_NET: LSTM(4096 steps, H=512) + CNN branch + MLP head.
// Round 11: single fused persistent kernel (256 blocks = 256 CUs).
//   blocks 0-63  : r7-exact LSTM (exchange-publish + coherent-poll, 1.57us/step)
//                  gated on per-64-row G-tile readiness flags.
//   blocks 64-255: gemm_g tiles m-major (release per m-tile) -> CNN chain with
//                  release/acquire counter barriers -> wait LSTM -> fc1+head.
// Hides the previously-serial ~0.5ms of gemm_g + CNN under the LSTM shadow.
// Cross-block visibility: agent-scope release (buffer_wbl2) / acquire (inv).
// Co-residency: waves_per_eu(1,1), 256 threads -> exactly 1 block/CU x 256.
// ---------------------------------------------------------------------------

#define HSZ    512
#define ESZ    300
#define NBLK   64     // LSTM blocks
#define NBCNN  192    // CNN/G blocks

typedef unsigned long long u64t;
typedef float f32x4 __attribute__((ext_vector_type(4)));
typedef unsigned u32x4 __attribute__((ext_vector_type(4)));

__device__ __forceinline__ float sigf(float x) {
    return 1.f / (1.f + __expf(-x));
}
__device__ __forceinline__ float tanh_fast(float x) {
    return 1.f - 2.f / (__expf(2.f * x) + 1.f);
}

// opaque global load: compiler cannot rematerialize -> must keep in VGPRs
__device__ __forceinline__ f32x4 ldg_f4(const f32x4* p) {
    f32x4 v;
    asm volatile("global_load_dwordx4 %0, %1, off\n\ts_waitcnt vmcnt(0)"
                 : "=v"(v) : "v"(p));
    return v;
}
// coherent 16B poll load (bypasses L1/L2 caching; served at coherence point)
__device__ __forceinline__ u32x4 ld_x4_coh(const void* p) {
    u32x4 v;
    asm volatile("global_load_dwordx4 %0, %1, off sc0 sc1\n\ts_waitcnt vmcnt(0)"
                 : "=v"(v) : "v"(p) : "memory");
    return v;
}
#define AGLD64(p) __hip_atomic_load((p), __ATOMIC_RELAXED, __HIP_MEMORY_SCOPE_AGENT)

__device__ __forceinline__ void rel_add(int* p) {
    __hip_atomic_fetch_add(p, 1, __ATOMIC_RELEASE, __HIP_MEMORY_SCOPE_AGENT);
}
__device__ __forceinline__ int rlx_ld(const int* p) {
    return __hip_atomic_load(p, __ATOMIC_RELAXED, __HIP_MEMORY_SCOPE_AGENT);
}
__device__ __forceinline__ int acq_ld(const int* p) {
    return __hip_atomic_load(p, __ATOMIC_ACQUIRE, __HIP_MEMORY_SCOPE_AGENT);
}

// barrier among the NBCNN CNN blocks; 'expected' is monotonic (k * NBCNN)
__device__ __forceinline__ void cnn_barrier(int* cnt, int expected) {
    __syncthreads();                 // drain this block's stores (vmcnt 0)
    if (threadIdx.x == 0) {
        rel_add(cnt);                // wbl2 + release add
        while (rlx_ld(cnt) < expected) __builtin_amdgcn_s_sleep(2);
        (void)acq_ld(cnt);           // invalidate -> fresh reads afterwards
    }
    __syncthreads();
}

// ---------------------------------------------------------------------------
// device GEMM tiles (shared arrays passed in; whole block participates)
// ---------------------------------------------------------------------------
__device__ void gemm_g_tile(const float* __restrict__ A, const float* __restrict__ B,
                            const float* __restrict__ bi, const float* __restrict__ bh,
                            float* __restrict__ C, int M, int N, int K,
                            int m0, int n0, float (&As)[16][65], float (&Bs)[16][65])
{
    const int tid = threadIdx.x;
    const int tm = (tid >> 4) * 4, tn = (tid & 15) * 4;
    const int lr = tid >> 2;
    const int lk = (tid & 3) * 4;
    float acc[4][4] = {};

    for (int kk = 0; kk < K; kk += 16) {
        int k0 = kk + lk;
        float4 av = {0,0,0,0}, bv = {0,0,0,0};
        if (m0 + lr < M) {
            const float* ap = A + (size_t)(m0 + lr) * K;
            if (k0 + 3 < K) av = *(const float4*)(ap + k0);
            else {
                float tmp[4];
#pragma unroll
                for (int e = 0; e < 4; ++e) tmp[e] = (k0 + e < K) ? ap[k0 + e] : 0.f;
                av.x = tmp[0]; av.y = tmp[1]; av.z = tmp[2]; av.w = tmp[3];
            }
        }
        {
            const float* bp = B + (size_t)(n0 + lr) * K;
            if (k0 + 3 < K) bv = *(const float4*)(bp + k0);
            else {
                float tmp[4];
#pragma unroll
                for (int e = 0; e < 4; ++e) tmp[e] = (k0 + e < K) ? bp[k0 + e] : 0.f;
                bv.x = tmp[0]; bv.y = tmp[1]; bv.z = tmp[2]; bv.w = tmp[3];
            }
        }
        As[lk+0][lr] = av.x; As[lk+1][lr] = av.y;
        As[lk+2][lr] = av.z; As[lk+3][lr] = av.w;
        Bs[lk+0][lr] = bv.x; Bs[lk+1][lr] = bv.y;
        Bs[lk+2][lr] = bv.z; Bs[lk+3][lr] = bv.w;
        __syncthreads();
#pragma unroll
        for (int k2 = 0; k2 < 16; ++k2) {
            float a0 = As[k2][tm], a1 = As[k2][tm+1], a2 = As[k2][tm+2], a3 = As[k2][tm+3];
            float b0 = Bs[k2][tn], b1 = Bs[k2][tn+1], b2 = Bs[k2][tn+2], b3 = Bs[k2][tn+3];
            acc[0][0]+=a0*b0; acc[0][1]+=a0*b1; acc[0][2]+=a0*b2; acc[0][3]+=a0*b3;
            acc[1][0]+=a1*b0; acc[1][1]+=a1*b1; acc[1][2]+=a1*b2; acc[1][3]+=a1*b3;
            acc[2][0]+=a2*b0; acc[2][1]+=a2*b1; acc[2][2]+=a2*b2; acc[2][3]+=a2*b3;
            acc[3][0]+=a3*b0; acc[3][1]+=a3*b1; acc[3][2]+=a3*b2; acc[3][3]+=a3*b3;
        }
        __syncthreads();
    }
#pragma unroll
    for (int i = 0; i < 4; ++i) {
        int m = m0 + tm + i;
        if (m >= M) break;
#pragma unroll
        for (int jj = 0; jj < 4; ++jj) {
            int n = n0 + tn + jj;
            C[(size_t)m * N + n] = acc[i][jj] + bi[n] + bh[n];
        }
    }
}

__device__ void gemm32_tile(const float* __restrict__ A, const float* __restrict__ B,
                            const float* __restrict__ bias, float* __restrict__ C,
                            int M, int N, int K, int m0, int n0,
                            float (&As)[32][33], float (&Bs)[32][33])
{
    const int tid = threadIdx.x;
    const int tn = (tid & 15) * 2, tm = (tid >> 4) * 2;
    float a00 = 0, a01 = 0, a10 = 0, a11 = 0;

    for (int kk = 0; kk < K; kk += 32) {
        const int k = tid & 31, r = tid >> 5;
#pragma unroll
        for (int jj = 0; jj < 4; ++jj) {
            int m = r + jj * 8;
            As[k][m] = (kk + k < K && m0 + m < M) ? A[(size_t)(m0+m)*K + kk+k] : 0.f;
            Bs[k][m] = (kk + k < K && n0 + m < N) ? B[(size_t)(n0+m)*K + kk+k] : 0.f;
        }
        __syncthreads();
#pragma unroll
        for (int k2 = 0; k2 < 32; ++k2) {
            float x0 = As[k2][tm], x1 = As[k2][tm+1];
            float y0 = Bs[k2][tn], y1 = Bs[k2][tn+1];
            a00 += x0*y0; a01 += x0*y1; a10 += x1*y0; a11 += x1*y1;
        }
        __syncthreads();
    }
    const int m = m0 + tm, n = n0 + tn;
    if (m < M) {
        if (n     < N) C[(size_t)m*N + n]     = a00 + bias[n];
        if (n + 1 < N) C[(size_t)m*N + n + 1] = a01 + bias[n+1];
    }
    if (m + 1 < M) {
        if (n     < N) C[(size_t)(m+1)*N + n]     = a10 + bias[n];
        if (n + 1 < N) C[(size_t)(m+1)*N + n + 1] = a11 + bias[n+1];
    }
}

// ---------------------------------------------------------------------------
// Fused mega kernel.
// ---------------------------------------------------------------------------
__global__ __attribute__((amdgpu_flat_work_group_size(256, 256),
                          amdgpu_waves_per_eu(1, 1)))
void mega_kernel(
    const float* __restrict__ inputs, const float* __restrict__ w_ih,
    const float* __restrict__ w_hh, const float* __restrict__ b_ih,
    const float* __restrict__ b_hh,
    const float* __restrict__ c1w, const float* __restrict__ c1b,
    const float* __restrict__ c2w, const float* __restrict__ c2b,
    const float* __restrict__ c3w, const float* __restrict__ c3b,
    const float* __restrict__ c4w, const float* __restrict__ c4b,
    const float* __restrict__ fc1w, const float* __restrict__ fc1b,
    const float* __restrict__ fc2w, const float* __restrict__ fc2b,
    const float* __restrict__ fc3w, const float* __restrict__ fc3b,
    float* __restrict__ out,
    u64t* hpack, float* hmean, int* gtile_cnt, int* stage_cnt, int* lstm_done,
    float* G, float* X1, float* C1, float* s1, float* X2, float* C2,
    float* s2, float* X3, float* C3, float* s3, float* X4, float* C4,
    float* yb, float* x2buf, int T)
{
    __shared__ float hlds[2][512];
    __shared__ float AsG[16][65];
    __shared__ float BsG[16][65];
    __shared__ float As[32][33];
    __shared__ float Bs[32][33];
    __shared__ float xhead[32];

    const int tid = threadIdx.x;
    const int bid = blockIdx.x;

    if (bid < NBLK) {
        // ================= LSTM (r7-exact) + G-tile gating =================
        const int lane = tid & 63;
        const int wave = tid >> 6;
        const int dot  = tid >> 3;
        const int seg  = tid & 7;
        const int gate = dot & 3;
        const int jl   = dot >> 2;
        const int j    = bid * 8 + jl;
        const int row  = gate * HSZ + j;

        f32x4 wh[16];
        {
            const f32x4* whp = (const f32x4*)(w_hh + (size_t)row * HSZ);
#pragma unroll
            for (int i = 0; i < 16; ++i)
                wh[i] = ldg_f4(whp + (seg * 16 + ((i + seg) & 15)));
        }

        float c = 0.f, hsum = 0.f;
        const int l0 = lane & 32;
        const int j2 = bid * 8 + wave * 2 + (lane >> 5);

        for (int s = 1; s <= T; ++s) {
            const int t = s - 1, p = t & 1;

            // gate on G m-tile readiness (32 col-tiles per 64-row tile)
            if ((t & 63) == 0) {
                if (tid == 0) {
                    int* gc = &gtile_cnt[t >> 6];
                    while (rlx_ld(gc) < 32) __builtin_amdgcn_s_sleep(1);
                    (void)acq_ld(gc);   // invalidate -> fresh G reads
                }
                __syncthreads();
            }

            float acc = (seg == 0) ? G[(size_t)t * (4 * HSZ) + row] : 0.f;

            // poll h_{t}: one dwordx4 = my two u64 words (slot p, tag t)
            {
                const u32x4* pp = (const u32x4*)(hpack + (size_t)p * HSZ) + tid;
                const unsigned tg = (unsigned)t;
                u32x4 v = ld_x4_coh(pp);
                while (v[1] != tg || v[3] != tg)
                    v = ld_x4_coh(pp);
                hlds[p][2 * tid]     = __uint_as_float(v[0]);
                hlds[p][2 * tid + 1] = __uint_as_float(v[2]);
            }
            __syncthreads();

            {
                const f32x4* hp = (const f32x4*)(&hlds[p][0]);
#pragma unroll
                for (int i = 0; i < 16; ++i) {
                    f32x4 h4 = hp[seg * 16 + ((i + seg) & 15)];
                    acc += wh[i][0] * h4[0] + wh[i][1] * h4[1] +
                           wh[i][2] * h4[2] + wh[i][3] * h4[3];
                }
            }
            acc += __shfl_xor(acc, 4, 64);
            acc += __shfl_xor(acc, 2, 64);
            acc += __shfl_xor(acc, 1, 64);
            float gi = __shfl(acc, l0 + 0,  64);
            float gf = __shfl(acc, l0 + 8,  64);
            float gg = __shfl(acc, l0 + 16, 64);
            float go = __shfl(acc, l0 + 24, 64);

            float is = sigf(gi), fs = sigf(gf), os = sigf(go);
            float gt = tanh_fast(gg);
            c = fs * c + is * gt;
            float h = os * tanh_fast(c);

            if ((lane & 31) == 0) {
                hsum += h;
                union { float f; unsigned u; } hv; hv.f = h;
                u64t pk = ((u64t)(unsigned)s << 32) | (u64t)hv.u;
                u64t old = __hip_atomic_exchange(
                    &hpack[(size_t)(s & 1) * HSZ + j2], pk,
                    __ATOMIC_RELAXED, __HIP_MEMORY_SCOPE_AGENT);
                asm volatile("" :: "v"(old));   // keep the RMW
            }
        }

        if ((lane & 31) == 0)
            hmean[j2] = hsum * (1.f / (float)T);
        __syncthreads();                 // drain hmean stores
        if (tid == 0) rel_add(lstm_done);
        return;
    }

    // ======================= CNN / G producer blocks =======================
    const int cb = bid - NBLK;          // 0..191
    int exp = NBCNN;

    // ---- stage A: G = inputs*w_ih^T + biases, m-major tiles ----
    {
        const int n_mt = (T + 63) >> 6;
        const int total = n_mt * 32;    // 32 col-tiles of 64
        for (int tile = cb; tile < total; tile += NBCNN) {
            const int mt = tile >> 5, nt = tile & 31;
            gemm_g_tile(inputs, w_ih, b_ih, b_hh, G, T, 2048, ESZ,
                        mt * 64, nt * 64, AsG, BsG);
            __syncthreads();            // drain C stores before release
            if (tid == 0) rel_add(&gtile_cnt[mt]);
        }
    }

    // ---- stage 1: im2col1 ----
    for (int idx = cb * 256 + tid; idx < 512 * 2100; idx += NBCNN * 256) {
        int t_ = idx / 2100, k = idx - t_ * 2100;
        int dt = k / 300, e = k - dt * 300;
        int tt = t_ + dt - 3;
        X1[idx] = (tt >= 0 && tt < 512) ? inputs[tt * 300 + e] : 0.f;
    }
    cnn_barrier(stage_cnt, exp); exp += NBCNN;

    // ---- stage 2: conv1 GEMM (512x256, K=2100): 16x8 tiles ----
    for (int tile = cb; tile < 128; tile += NBCNN)
        gemm32_tile(X1, c1w, c1b, C1, 512, 256, 2100,
                    (tile >> 3) * 32, (tile & 7) * 32, As, Bs);
    cnn_barrier(stage_cnt, exp); exp += NBCNN;

    // ---- stage 3: pool+sig -> s1[256][256] ----
    for (int idx = cb * 256 + tid; idx < 256 * 256; idx += NBCNN * 256) {
        int c_ = idx >> 8, tp = idx & 255;
        float a = C1[(2 * tp) * 256 + c_], b = C1[(2 * tp + 1) * 256 + c_];
        s1[idx] = sigf(fmaxf(a, b));
    }
    cnn_barrier(stage_cnt, exp); exp += NBCNN;

    // ---- stage 4: im2col2 (L=256,Cin=256,KW=5,pad=2) ----
    for (int idx = cb * 256 + tid; idx < 256 * 1280; idx += NBCNN * 256) {
        int t_ = idx / 1280, r = idx - t_ * 1280;
        int c_ = r / 5, dk = r - c_ * 5;
        int tt = t_ + dk - 2;
        X2[idx] = (tt >= 0 && tt < 256) ? s1[c_ * 256 + tt] : 0.f;
    }
    cnn_barrier(stage_cnt, exp); exp += NBCNN;

    // ---- stage 5: conv2 GEMM (256x64, K=1280): 8x2 tiles ----
    for (int tile = cb; tile < 16; tile += NBCNN)
        gemm32_tile(X2, c2w, c2b, C2, 256, 64, 1280,
                    (tile >> 1) * 32, (tile & 1) * 32, As, Bs);
    cnn_barrier(stage_cnt, exp); exp += NBCNN;

    // ---- stage 6: pool+sig -> s2[64][128] ----
    for (int idx = cb * 256 + tid; idx < 64 * 128; idx += NBCNN * 256) {
        int c_ = idx / 128, tp = idx - c_ * 128;
        float a = C2[(2 * tp) * 64 + c_], b = C2[(2 * tp + 1) * 64 + c_];
        s2[idx] = sigf(fmaxf(a, b));
    }
    cnn_barrier(stage_cnt, exp); exp += NBCNN;

    // ---- stage 7: im2col3 (L=128,Cin=64,KW=3,pad=1) ----
    for (int idx = cb * 256 + tid; idx < 128 * 192; idx += NBCNN * 256) {
        int t_ = idx / 192, r = idx - t_ * 192;
        int c_ = r / 3, dk = r - c_ * 3;
        int tt = t_ + dk - 1;
        X3[idx] = (tt >= 0 && tt < 128) ? s2[c_ * 128 + tt] : 0.f;
    }
    cnn_barrier(stage_cnt, exp); exp += NBCNN;

    // ---- stage 8: conv3 GEMM (128x256, K=192): 4x8 tiles ----
    for (int tile = cb; tile < 32; tile += NBCNN)
        gemm32_tile(X3, c3w, c3b, C3, 128, 256, 192,
                    (tile >> 3) * 32, (tile & 7) * 32, As, Bs);
    cnn_barrier(stage_cnt, exp); exp += NBCNN;

    // ---- stage 9: pool+sig -> s3[256][64] ----
    for (int idx = cb * 256 + tid; idx < 256 * 64; idx += NBCNN * 256) {
        int c_ = idx / 64, tp = idx - c_ * 64;
        float a = C3[(2 * tp) * 256 + c_], b = C3[(2 * tp + 1) * 256 + c_];
        s3[idx] = sigf(fmaxf(a, b));
    }
    cnn_barrier(stage_cnt, exp); exp += NBCNN;

    // ---- stage 10: transpose -> X4[64][256] ----
    for (int idx = cb * 256 + tid; idx < 64 * 256; idx += NBCNN * 256) {
        int t_ = idx >> 8, c_ = idx & 255;
        X4[idx] = s3[c_ * 64 + t_];
    }
    cnn_barrier(stage_cnt, exp); exp += NBCNN;

    // ---- stage 11: conv4 GEMM (64x16, K=256): 2x1 tiles ----
    for (int tile = cb; tile < 2; tile += NBCNN)
        gemm32_tile(X4, c4w, c4b, C4, 64, 16, 256, tile * 32, 0, As, Bs);
    cnn_barrier(stage_cnt, exp); exp += NBCNN;

    // ---- stage 12: sigy -> yb[1024] ----
    for (int idx = cb * 256 + tid; idx < 1024; idx += NBCNN * 256) {
        int o = idx >> 6, t_ = idx & 63;
        yb[idx] = sigf(C4[t_ * 16 + o]);
    }
    cnn_barrier(stage_cnt, exp); exp += NBCNN;

    // ---- wait for LSTM completion (hmean) ----
    if (tid == 0) {
        while (rlx_ld(lstm_done) < NBLK) __builtin_amdgcn_s_sleep(8);
        (void)acq_ld(lstm_done);
    }
    __syncthreads();

    // ---- stage 13: fc1 (128 outputs, one per block cb<128, wave 0) ----
    if (cb < 128 && tid < 64) {
        float a = 0.f;
        for (int i = tid; i < 1536; i += 64) {
            float xv = (i < 512) ? hmean[i] : yb[i - 512];
            a += xv * fc1w[cb * 1536 + i];
        }
#pragma unroll
        for (int off = 32; off; off >>= 1) a += __shfl_xor(a, off, 64);
        if (tid == 0) x2buf[cb] = sigf(a + fc1b[cb]);
    }
    cnn_barrier(stage_cnt, exp); exp += NBCNN;

    // ---- head: fc2 (32x128) + fc3 (1x32) on block cb==0 ----
    if (cb == 0) {
        if (tid < 32) {
            float a = 0.f;
            for (int i = 0; i < 128; ++i) a += x2buf[i] * fc2w[tid * 128 + i];
            xhead[tid] = sigf(a + fc2b[tid]);
        }
        __syncthreads();
        if (tid == 0) {
            float a = 0.f;
            for (int i = 0; i < 32; ++i) a += xhead[i] * fc3w[i];
            out[0] = sigf(a + fc3b[0]);
        }
    }
}

// ---------------------------------------------------------------------------
// Fallback path (ws too small for G): r2-proven standalone kernels.
// ---------------------------------------------------------------------------
__global__ __launch_bounds__(256, 1) void lstm_small(
    const float* __restrict__ inputs, const float* __restrict__ w_ih,
    const float* __restrict__ w_hh, const float* __restrict__ b_ih,
    const float* __restrict__ b_hh,
    u64t* hpack, float* hmean, int T)
{
    __shared__ float hlds[2][512];
    const int tid  = threadIdx.x;
    const int lane = tid & 63;
    const int wave = tid >> 6;
    const int dot  = tid >> 3;
    const int seg  = tid & 7;
    const int gate = dot & 3;
    const int jl   = dot >> 2;
    const int j    = blockIdx.x * 8 + jl;
    const int row  = gate * HSZ + j;

    f32x4 wh[16]; int offs[16];
    const f32x4* whp = (const f32x4*)(w_hh + (size_t)row * HSZ);
#pragma unroll
    for (int i = 0; i < 16; ++i) {
        int cc = seg * 16 + ((i + seg) & 15);
        offs[i] = cc;
        wh[i] = ldg_f4(whp + cc);
    }
    const int base = (seg == 7) ? 260 : seg * 40;
    float wx[40];
#pragma unroll
    for (int i = 0; i < 40; ++i) {
        bool valid = (seg < 7) || (i >= 20);
        wx[i] = valid ? w_ih[(size_t)row * ESZ + base + i] : 0.f;
    }
    const float bias = b_ih[row] + b_hh[row];

    float c = 0.f, hsum = 0.f;
    const int l0 = lane & 32;
    const int j2 = blockIdx.x * 8 + wave * 2 + (lane >> 5);

    for (int s = 1; s <= T; ++s) {
        const int t = s - 1, p = t & 1;
        float acc = (seg == 0) ? bias : 0.f;
        const float4* xp4 = (const float4*)(inputs + (size_t)t * ESZ + base);
#pragma unroll
        for (int i4 = 0; i4 < 10; ++i4) {
            float4 x4 = xp4[i4];
            acc += wx[i4*4+0]*x4.x + wx[i4*4+1]*x4.y +
                   wx[i4*4+2]*x4.z + wx[i4*4+3]*x4.w;
        }
        {
            u64t* w0p = hpack + (size_t)p * HSZ + tid;
            u64t* w1p = w0p + 256;
            const unsigned tg = (unsigned)t;
            u64t v0 = AGLD64(w0p), v1 = AGLD64(w1p);
            bool r0 = false, r1 = false;
            while (true) {
                r0 = r0 || ((unsigned)(v0 >> 32) == tg);
                r1 = r1 || ((unsigned)(v1 >> 32) == tg);
                if (r0 && r1) break;
                u64t n0 = AGLD64(w0p), n1 = AGLD64(w1p);
                if (!r0) v0 = n0;
                if (!r1) v1 = n1;
            }
            hlds[p][tid]       = __uint_as_float((unsigned)v0);
            hlds[p][tid + 256] = __uint_as_float((unsigned)v1);
        }
        __syncthreads();
        const f32x4* hp = (const f32x4*)(&hlds[p][0]);
#pragma unroll
        for (int i = 0; i < 16; ++i) {
            f32x4 h4 = hp[offs[i]];
            acc += wh[i][0]*h4[0] + wh[i][1]*h4[1] + wh[i][2]*h4[2] + wh[i][3]*h4[3];
        }
        acc += __shfl_xor(acc, 4, 64);
        acc += __shfl_xor(acc, 2, 64);
        acc += __shfl_xor(acc, 1, 64);
        float gi = __shfl(acc, l0 + 0,  64);
        float gf = __shfl(acc, l0 + 8,  64);
        float gg = __shfl(acc, l0 + 16, 64);
        float go = __shfl(acc, l0 + 24, 64);
        float is = sigf(gi), fs = sigf(gf), os = sigf(go);
        float gt = tanh_fast(gg);
        c = fs * c + is * gt;
        float h = os * tanh_fast(c);
        if ((lane & 31) == 0) {
            union { float f; unsigned u; } hv; hv.f = h;
            __hip_atomic_store(&hpack[(size_t)(s & 1) * HSZ + j2],
                               ((u64t)(unsigned)s << 32) | (u64t)hv.u,
                               __ATOMIC_RELAXED, __HIP_MEMORY_SCOPE_AGENT);
            hsum += h;
        }
    }
    if ((lane & 31) == 0) hmean[j2] = hsum * (1.f / (float)T);
}

__global__ __launch_bounds__(256) void gemm32(
    const float* __restrict__ A, const float* __restrict__ B,
    const float* __restrict__ bias, float* __restrict__ C,
    int M, int N, int K)
{
    __shared__ float As[32][33];
    __shared__ float Bs[32][33];
    gemm32_tile(A, B, bias, C, M, N, K, blockIdx.y * 32, blockIdx.x * 32, As, Bs);
}

__global__ void im2col1(const float* __restrict__ in, float* __restrict__ X)
{
    int idx = blockIdx.x * 256 + threadIdx.x;
    if (idx >= 512 * 2100) return;
    int t = idx / 2100, k = idx - t * 2100;
    int dt = k / 300, e = k - dt * 300;
    int tt = t + dt - 3;
    X[idx] = (tt >= 0 && tt < 512) ? in[tt * 300 + e] : 0.f;
}

__global__ void im2colN(const float* __restrict__ S, float* __restrict__ X,
                        int L, int Cin, int KW, int pad, int total)
{
    int idx = blockIdx.x * 256 + threadIdx.x;
    if (idx >= total) return;
    int KC = Cin * KW;
    int t = idx / KC, r = idx - t * KC;
    int c = r / KW, dk = r - c * KW;
    int tt = t + dk - pad;
    X[idx] = (tt >= 0 && tt < L) ? S[c * L + tt] : 0.f;
}

__global__ void transpose4(const float* __restrict__ S, float* __restrict__ X)
{
    int idx = blockIdx.x * 256 + threadIdx.x;
    if (idx >= 64 * 256) return;
    int t = idx >> 8, c = idx & 255;
    X[idx] = S[c * 64 + t];
}

__global__ void poolsig(const float* __restrict__ Cin_, float* __restrict__ S,
                        int Cch, int LP)
{
    int idx = blockIdx.x * 256 + threadIdx.x;
    if (idx >= Cch * LP) return;
    int c = idx / LP, tp = idx - c * LP;
    float a = Cin_[(2 * tp) * Cch + c];
    float b = Cin_[(2 * tp + 1) * Cch + c];
    S[idx] = sigf(fmaxf(a, b));
}

__global__ void sigy(const float* __restrict__ C4, float* __restrict__ y)
{
    int idx = blockIdx.x * 256 + threadIdx.x;
    if (idx >= 1024) return;
    int o = idx >> 6, t = idx & 63;
    y[idx] = sigf(C4[t * 16 + o]);
}

__global__ void fc1_kernel(const float* __restrict__ hmean,
                           const float* __restrict__ y,
                           const float* __restrict__ w,
                           const float* __restrict__ b,
                           float* __restrict__ out)
{
    int k = blockIdx.x, lane = threadIdx.x;
    float a = 0.f;
    for (int i = lane; i < 1536; i += 64) {
        float xv = (i < 512) ? hmean[i] : y[i - 512];
        a += xv * w[k * 1536 + i];
    }
#pragma unroll
    for (int off = 32; off; off >>= 1) a += __shfl_xor(a, off, 64);
    if (lane == 0) out[k] = sigf(a + b[k]);
}

__global__ void head_kernel(const float* __restrict__ x2,
                            const float* __restrict__ w2, const float* __restrict__ b2,
                            const float* __restrict__ w3, const float* __restrict__ b3,
                            float* __restrict__ out)
{
    __shared__ float x3[32];
    int lane = threadIdx.x;
    if (lane < 32) {
        float a = 0.f;
        for (int i = 0; i < 128; ++i) a += x2[i] * w2[lane * 128 + i];
        x3[lane] = sigf(a + b2[lane]);
    }
    __syncthreads();
    if (lane == 0) {
        float a = 0.f;
        for (int i = 0; i < 32; ++i) a += x3[i] * w3[i];
        out[0] = sigf(a + b3[0]);
    }
}

extern "C" void kernel_launch(void* const* d_in, const int* in_sizes, int n_in,
                              void* d_out, int out_size, void* d_ws, size_t ws_size,
                              hipStream_t stream)
{
    const float* inputs = (const float*)d_in[0];
    const float* w_ih   = (const float*)d_in[1];
    const float* w_hh   = (const float*)d_in[2];
    const float* b_ih   = (const float*)d_in[3];
    const float* b_hh   = (const float*)d_in[4];
    const float* c1w    = (const float*)d_in[5];
    const float* c1b    = (const float*)d_in[6];
    const float* c2w    = (const float*)d_in[7];
    const float* c2b    = (const float*)d_in[8];
    const float* c3w    = (const float*)d_in[9];
    const float* c3b    = (const float*)d_in[10];
    const float* c4w    = (const float*)d_in[11];
    const float* c4b    = (const float*)d_in[12];
    const float* fc1w   = (const float*)d_in[13];
    const float* fc1b   = (const float*)d_in[14];
    const float* fc2w   = (const float*)d_in[15];
    const float* fc2b   = (const float*)d_in[16];
    const float* fc3w   = (const float*)d_in[17];
    const float* fc3b   = (const float*)d_in[18];
    float* out = (float*)d_out;
    const int T = in_sizes[0] / ESZ;   // 4096

    // ---- workspace layout ----
    // bytes [0, 8192)   : hpack (2*512 u64)
    // bytes [8192, 8704): gtile_cnt (128 int)
    // byte 8704: stage_cnt   8708: lstm_done   (zeroed each launch)
    // float 2560 (byte 10240): hmean(512); 3072: CNN buffers; then G.
    float* p         = (float*)d_ws;
    u64t*  hpack     = (u64t*)d_ws;
    int*   gtile_cnt = (int*)d_ws + 2048;
    int*   stage_cnt = (int*)d_ws + 2176;
    int*   lstm_done = (int*)d_ws + 2177;
    float* hmean = p + 2560;                   // 512
    float* X1 = p + 3072;                      // 512*2100 = 1075200
    float* C1 = X1 + 1075200;                  // 512*256
    float* s1 = C1 + 131072;                   // 256*256
    float* X2 = s1 + 65536;                    // 256*1280
    float* C2 = X2 + 327680;                   // 256*64
    float* s2 = C2 + 16384;                    // 64*128
    float* X3 = s2 + 8192;                     // 128*192
    float* C3 = X3 + 24576;                    // 128*256
    float* s3 = C3 + 32768;                    // 256*64
    float* X4 = s3 + 16384;                    // 64*256
    float* C4 = X4 + 16384;                    // 64*16
    float* yb = C4 + 1024;                     // 1024
    float* x2 = yb + 1024;                     // 128
    float* G  = x2 + 128;                      // T*2048 floats
    const size_t need_bytes = ((size_t)(x2 + 128 - p) + (size_t)T * 2048) * 4;
    const bool use_g = ws_size >= need_bytes;

    // zero h state + readiness flags + counters — replay-safe
    hipMemsetAsync(d_ws, 0, 10240, stream);

    if (use_g) {
        mega_kernel<<<256, 256, 0, stream>>>(
            inputs, w_ih, w_hh, b_ih, b_hh,
            c1w, c1b, c2w, c2b, c3w, c3b, c4w, c4b,
            fc1w, fc1b, fc2w, fc2b, fc3w, fc3b, out,
            hpack, hmean, gtile_cnt, stage_cnt, lstm_done,
            G, X1, C1, s1, X2, C2, s2, X3, C3, s3, X4, C4, yb, x2, T);
        return;
    }

    // -------- fallback: r2-proven separate kernels --------
    lstm_small<<<NBLK, 256, 0, stream>>>(
        inputs, w_ih, w_hh, b_ih, b_hh, hpack, hmean, T);

    im2col1<<<4200, 256, 0, stream>>>(inputs, X1);
    gemm32<<<dim3(8, 16), 256, 0, stream>>>(X1, c1w, c1b, C1, 512, 256, 2100);
    poolsig<<<256, 256, 0, stream>>>(C1, s1, 256, 256);

    im2colN<<<1280, 256, 0, stream>>>(s1, X2, 256, 256, 5, 2, 256 * 1280);
    gemm32<<<dim3(2, 8), 256, 0, stream>>>(X2, c2w, c2b, C2, 256, 64, 1280);
    poolsig<<<32, 256, 0, stream>>>(C2, s2, 64, 128);

    im2colN<<<96, 256, 0, stream>>>(s2, X3, 128, 64, 3, 1, 128 * 192);
    gemm32<<<dim3(8, 4), 256, 0, stream>>>(X3, c3w, c3b, C3, 128, 256, 192);
    poolsig<<<64, 256, 0, stream>>>(C3, s3, 256, 64);

    transpose4<<<64, 256, 0, stream>>>(s3, X4);
    gemm32<<<dim3(1, 2), 256, 0, stream>>>(X4, c4w, c4b, C4, 64, 16, 256);
    sigy<<<4, 256, 0, stream>>>(C4, yb);

    fc1_kernel<<<128, 64, 0, stream>>>(hmean, yb, fc1w, fc1b, x2);
    head_kernel<<<1, 64, 0, stream>>>(x2, fc2w, fc2b, fc3w, fc3b, out);
}